// Round 5
// baseline (6776.250 us; speedup 1.0000x reference)
//
#include <hip/hip_runtime.h>
#include <cstdio>

// ---------------------------------------------------------------------------
// MyGCN: 3-layer GraphConv GCN on MI355X.
// Round 5:
//  - precision reverted to round-3 (fp32 X/M/y, bf16 H only) for absmax margin
//  - aggregation rebuilt as col-swept scatter-accumulate: edges sorted by col
//    within 98-row buckets; one block per bucket accumulates into a 50KB fp32
//    LDS tile (atomicAdd, even/odd slot permutation -> conflict-free banks).
//    All concurrent blocks sweep cols in lockstep -> moving L2 window.
//  - GraphNorm stats on M computed from the LDS tile (3 reduces eliminated)
// GEMMs: bf16 MFMA 16x16x32, GraphNorm folded to per-feature affine applied
// during LDS staging (round-3 kernel).
// ---------------------------------------------------------------------------

#define HID 128

typedef __attribute__((ext_vector_type(8))) short short8;
typedef __attribute__((ext_vector_type(4))) float floatx4;

__device__ __forceinline__ unsigned short f2bf(float f) {
    unsigned u = __float_as_uint(f);
    unsigned r = (u + 0x7FFFu + ((u >> 16) & 1u)) >> 16;  // RNE
    return (unsigned short)r;
}
__device__ __forceinline__ float bflo(unsigned u) { return __uint_as_float(u << 16); }
__device__ __forceinline__ float bfhi(unsigned u) { return __uint_as_float(u & 0xFFFF0000u); }

// ---------------- bucketed edge binning ----------------
#define NB 1024     // row buckets
#define RPB 98      // rows per bucket (1024*98 = 100352 >= N)
#define CAPB 4096   // edge capacity per bucket (mean 3125 + 17 sigma)
#define TILE_A 2048 // edges per block in pass A

// Pass A: bin edges by row bucket. binned[b*CAPB+i] = ((rl<<17)|col, ew_bits)
__global__ __launch_bounds__(256) void k_binA(
    const int* __restrict__ row, const int* __restrict__ col,
    const float* __restrict__ ew, int2* __restrict__ binned,
    unsigned* __restrict__ cursor, int E) {
    __shared__ int2 stag[TILE_A];
    __shared__ unsigned short bof[TILE_A];
    __shared__ unsigned hist[NB], scanned[NB], bump[NB];
    __shared__ int delta[NB];
    __shared__ unsigned scanw[256];
    int t = threadIdx.x;
    int tileBase = blockIdx.x * TILE_A;
    int tcnt = min(TILE_A, E - tileBase);

#pragma unroll
    for (int j = 0; j < 4; ++j) hist[t + j * 256] = 0;
    __syncthreads();

    int myb[8]; int2 myv[8];
#pragma unroll
    for (int i = 0; i < 8; ++i) {
        int idx = t + i * 256;
        if (idx < tcnt) {
            int e = tileBase + idx;
            unsigned r = (unsigned)row[e];
            int c = col[e];
            float w = ew[e];
            unsigned b = r / RPB;
            unsigned rl = r - b * RPB;
            myb[i] = (int)b;
            myv[i] = make_int2((int)((rl << 17) | (unsigned)c), __float_as_int(w));
            atomicAdd(&hist[b], 1u);
        } else {
            myb[i] = -1;
            myv[i] = make_int2(0, 0);
        }
    }
    __syncthreads();

    // exclusive scan over 1024 counters (4 per thread)
    unsigned h0 = hist[4 * t], h1 = hist[4 * t + 1], h2 = hist[4 * t + 2], h3 = hist[4 * t + 3];
    unsigned p = h0 + h1 + h2 + h3;
    scanw[t] = p;
    __syncthreads();
    for (int o = 1; o < 256; o <<= 1) {
        unsigned x = (t >= o) ? scanw[t - o] : 0u;
        __syncthreads();
        scanw[t] += x;
        __syncthreads();
    }
    unsigned excl = scanw[t] - p;
    scanned[4 * t] = excl;                 bump[4 * t] = excl;
    scanned[4 * t + 1] = excl + h0;        bump[4 * t + 1] = excl + h0;
    scanned[4 * t + 2] = excl + h0 + h1;   bump[4 * t + 2] = excl + h0 + h1;
    scanned[4 * t + 3] = excl + h0 + h1 + h2; bump[4 * t + 3] = excl + h0 + h1 + h2;
    __syncthreads();

    // reserve global regions (one atomic per non-empty bucket)
#pragma unroll
    for (int j = 0; j < 4; ++j) {
        int b = t + j * 256;
        unsigned c = hist[b];
        if (c) {
            unsigned old = atomicAdd(&cursor[b], c);
            delta[b] = (int)((unsigned)b * CAPB + old) - (int)scanned[b];
        }
    }
    __syncthreads();

    // place into bucket-ordered LDS staging
#pragma unroll
    for (int i = 0; i < 8; ++i) {
        if (myb[i] >= 0) {
            unsigned s = atomicAdd(&bump[myb[i]], 1u);
            stag[s] = myv[i];
            bof[s] = (unsigned short)myb[i];
        }
    }
    __syncthreads();

    // coalesced flush (consecutive i -> consecutive dst within bucket runs)
    for (int i = t; i < tcnt; i += 256) {
        int b = bof[i];
        int dst = delta[b] + i;
        if (dst < (b + 1) * CAPB) binned[dst] = stag[i];
    }
}

// Pass B (in-place): per-bucket weighted degree, then re-sort the bucket's
// edges by col (512-col histogram key) and scale w by inv_deg[row].
__global__ __launch_bounds__(256) void k_binB(
    int2* __restrict__ binned, const unsigned* __restrict__ cursor) {
    __shared__ int2 stag[CAPB];  // 32 KB
    __shared__ unsigned hist[256], bump[256], scanw[256];
    __shared__ float wsum[128], inv[128];
    int b = blockIdx.x, t = threadIdx.x;
    size_t base = (size_t)b * CAPB;
    unsigned cntb = min(cursor[b], (unsigned)CAPB);

    hist[t] = 0;
    if (t < 128) wsum[t] = 0.f;
    __syncthreads();
    for (unsigned i = t; i < cntb; i += 256) {
        int2 v = binned[base + i];
        stag[i] = v;
        atomicAdd(&hist[((unsigned)v.x & 0x1FFFFu) >> 9], 1u);
        atomicAdd(&wsum[(unsigned)v.x >> 17], __int_as_float(v.y));
    }
    __syncthreads();

    unsigned h = hist[t];
    scanw[t] = h;
    __syncthreads();
    for (int o = 1; o < 256; o <<= 1) {
        unsigned x = (t >= o) ? scanw[t - o] : 0u;
        __syncthreads();
        scanw[t] += x;
        __syncthreads();
    }
    bump[t] = scanw[t] - h;
    if (t < 128) {
        float d = wsum[t];
        d = (d < 0.5f) ? d + 1.0f : d;
        inv[t] = 1.0f / d;
    }
    __syncthreads();

    for (unsigned i = t; i < cntb; i += 256) {
        int2 v = stag[i];
        unsigned ck = ((unsigned)v.x & 0x1FFFFu) >> 9;
        unsigned pos = atomicAdd(&bump[ck], 1u);
        float w = __int_as_float(v.y) * inv[(unsigned)v.x >> 17];
        binned[base + pos] = make_int2(v.x, __float_as_int(w));
    }
}

// ---------------- embedding gather (fp32) ----------------
__global__ void k_gather(const int* __restrict__ x_idx, const float* __restrict__ emb,
                         float* __restrict__ X, int N) {
    int tid = blockIdx.x * blockDim.x + threadIdx.x;
    if (tid < N * 32) {
        int n = tid >> 5, c = tid & 31;
        ((float4*)X)[(size_t)n * 32 + c] =
            ((const float4*)emb)[(size_t)x_idx[n] * 32 + c];
    }
}

// ---------------- weight prep: transpose + bf16 ----------------
__global__ void k_prepw(const float* __restrict__ Wt, const float* __restrict__ Wc,
                        unsigned short* __restrict__ WtT, unsigned short* __restrict__ WcT) {
    int tid = blockIdx.x * blockDim.x + threadIdx.x;
    const int T1 = 3 * 128 * 128;
    const int T2 = 3 * 256 * 128;
    if (tid < T1) {
        int l = tid >> 14, rem = tid & 16383;
        int n = rem >> 7, k = rem & 127;
        WtT[tid] = f2bf(Wt[l * 16384 + k * 128 + n]);
    } else if (tid < T1 + T2) {
        int t2 = tid - T1;
        int l = t2 >> 15, rem = t2 & 32767;
        int n = rem >> 8, k = rem & 255;
        WcT[t2] = f2bf(Wc[l * 32768 + k * 128 + n]);
    }
}

// ---------------- bf16 MFMA GEMM (fp32 inputs, round-3 proven) ----------------
#define GM_ROWS 128
#define LDSP 136

__global__ __launch_bounds__(256) void k_gemm(
    const float* __restrict__ X1, const float* __restrict__ AB1, int relu1,
    const float* __restrict__ X2, const float* __restrict__ AB2, int relu2,
    const unsigned short* __restrict__ Wn, int Kpitch, int nstage,
    const float* __restrict__ bias, void* __restrict__ Y, int relu_out, int out_bf16,
    int N) {
    __shared__ unsigned short Ws[128 * LDSP];
    __shared__ unsigned short Xs[128 * LDSP];
    int t = threadIdx.x;
    int rowBase = blockIdx.x * GM_ROWS;
    int lane = t & 63, wave = t >> 6;
    int quad = lane >> 4, l16 = lane & 15;

    floatx4 acc[2][8];
#pragma unroll
    for (int i = 0; i < 2; ++i)
#pragma unroll
        for (int j = 0; j < 8; ++j) acc[i][j] = (floatx4){0.f, 0.f, 0.f, 0.f};

    int kg = (t & 15) * 8;
    int r0 = t >> 4;

    for (int s = 0; s < nstage; ++s) {
        const float* Xp = s ? X2 : X1;
        const float* ABp = s ? AB2 : AB1;
        int rl = s ? relu2 : relu1;
        int koff = s * 128;

#pragma unroll
        for (int j = 0; j < 8; ++j) {
            int n = r0 + 16 * j;
            *(short8*)&Ws[n * LDSP + kg] =
                *(const short8*)&Wn[(size_t)n * Kpitch + koff + kg];
        }
        floatx4 Av0 = {1.f, 1.f, 1.f, 1.f}, Av1 = Av0;
        floatx4 Bv0 = {0.f, 0.f, 0.f, 0.f}, Bv1 = Bv0;
        if (ABp) {
            Av0 = *(const floatx4*)&ABp[kg];
            Av1 = *(const floatx4*)&ABp[kg + 4];
            Bv0 = *(const floatx4*)&ABp[HID + kg];
            Bv1 = *(const floatx4*)&ABp[HID + kg + 4];
        }
#pragma unroll
        for (int j = 0; j < 8; ++j) {
            int r = r0 + 16 * j;
            int grow = rowBase + r;
            floatx4 x0 = {0.f, 0.f, 0.f, 0.f}, x1 = x0;
            if (grow < N) {
                x0 = *(const floatx4*)&Xp[(size_t)grow * HID + kg];
                x1 = *(const floatx4*)&Xp[(size_t)grow * HID + kg + 4];
            }
            if (ABp) {
#pragma unroll
                for (int c = 0; c < 4; ++c) {
                    x0[c] = fmaf(x0[c], Av0[c], Bv0[c]);
                    x1[c] = fmaf(x1[c], Av1[c], Bv1[c]);
                }
                if (rl) {
#pragma unroll
                    for (int c = 0; c < 4; ++c) {
                        x0[c] = fmaxf(x0[c], 0.f);
                        x1[c] = fmaxf(x1[c], 0.f);
                    }
                }
            }
            short8 st;
            st[0] = (short)f2bf(x0[0]); st[1] = (short)f2bf(x0[1]);
            st[2] = (short)f2bf(x0[2]); st[3] = (short)f2bf(x0[3]);
            st[4] = (short)f2bf(x1[0]); st[5] = (short)f2bf(x1[1]);
            st[6] = (short)f2bf(x1[2]); st[7] = (short)f2bf(x1[3]);
            *(short8*)&Xs[r * LDSP + kg] = st;
        }
        __syncthreads();

#pragma unroll
        for (int ks = 0; ks < 4; ++ks) {
            int kb = ks * 32 + quad * 8;
            short8 a0 = *(const short8*)&Xs[(wave * 32 + l16) * LDSP + kb];
            short8 a1 = *(const short8*)&Xs[(wave * 32 + 16 + l16) * LDSP + kb];
#pragma unroll
            for (int ni = 0; ni < 8; ++ni) {
                short8 b = *(const short8*)&Ws[(ni * 16 + l16) * LDSP + kb];
                acc[0][ni] = __builtin_amdgcn_mfma_f32_16x16x32_bf16(a0, b, acc[0][ni], 0, 0, 0);
                acc[1][ni] = __builtin_amdgcn_mfma_f32_16x16x32_bf16(a1, b, acc[1][ni], 0, 0, 0);
            }
        }
        __syncthreads();
    }

#pragma unroll
    for (int mi = 0; mi < 2; ++mi) {
#pragma unroll
        for (int ni = 0; ni < 8; ++ni) {
            int gcol = ni * 16 + l16;
            float bv = bias[gcol];
#pragma unroll
            for (int reg = 0; reg < 4; ++reg) {
                int grow = rowBase + wave * 32 + mi * 16 + quad * 4 + reg;
                if (grow < N) {
                    float v = acc[mi][ni][reg] + bv;
                    if (relu_out) v = fmaxf(v, 0.f);
                    if (out_bf16)
                        ((unsigned short*)Y)[(size_t)grow * HID + gcol] = f2bf(v);
                    else
                        ((float*)Y)[(size_t)grow * HID + gcol] = v;
                }
            }
        }
    }
}

// ---------------- col-swept scatter-accumulate aggregation ----------------
// One block per 98-row bucket. Edges pre-sorted by col -> all concurrent
// blocks sweep H in ascending col order (moving L2 window). fp32 accumulator
// tile in LDS; feature f lives at slot (f>>1) + (f&1)*64 so both per-edge
// atomicAdd instructions are 2-lanes-per-bank (conflict-free).
// Fused GraphNorm stats (sum, sumsq per feature) from the LDS tile.
#define AGT_LDS (RPB * HID)

__global__ __launch_bounds__(512) void k_aggT(
    const unsigned short* __restrict__ H, const int2* __restrict__ es,
    const unsigned* __restrict__ cursor, float* __restrict__ M,
    float* __restrict__ Spart, int N) {
    __shared__ float accum[AGT_LDS];  // 50,176 B
    int b = blockIdx.x, t = threadIdx.x;
    for (int i = t; i < AGT_LDS; i += 512) accum[i] = 0.f;
    __syncthreads();

    int wv = t >> 6, lane = t & 63;
    unsigned cntb = min(cursor[b], (unsigned)CAPB);
    size_t base = (size_t)b * CAPB;
    int fo = lane * 2;

    unsigned i = wv;
    for (; i + 24 < cntb; i += 32) {
        int2 e0 = es[base + i];
        int2 e1 = es[base + i + 8];
        int2 e2 = es[base + i + 16];
        int2 e3 = es[base + i + 24];
        unsigned c0 = (unsigned)e0.x & 0x1FFFFu, r0 = (unsigned)e0.x >> 17;
        unsigned c1 = (unsigned)e1.x & 0x1FFFFu, r1 = (unsigned)e1.x >> 17;
        unsigned c2 = (unsigned)e2.x & 0x1FFFFu, r2 = (unsigned)e2.x >> 17;
        unsigned c3 = (unsigned)e3.x & 0x1FFFFu, r3 = (unsigned)e3.x >> 17;
        unsigned h0 = *(const unsigned*)&H[(size_t)c0 * HID + fo];
        unsigned h1 = *(const unsigned*)&H[(size_t)c1 * HID + fo];
        unsigned h2 = *(const unsigned*)&H[(size_t)c2 * HID + fo];
        unsigned h3 = *(const unsigned*)&H[(size_t)c3 * HID + fo];
        float w0 = __int_as_float(e0.y), w1 = __int_as_float(e1.y);
        float w2 = __int_as_float(e2.y), w3 = __int_as_float(e3.y);
        atomicAdd(&accum[r0 * HID + lane], w0 * bflo(h0));
        atomicAdd(&accum[r0 * HID + 64 + lane], w0 * bfhi(h0));
        atomicAdd(&accum[r1 * HID + lane], w1 * bflo(h1));
        atomicAdd(&accum[r1 * HID + 64 + lane], w1 * bfhi(h1));
        atomicAdd(&accum[r2 * HID + lane], w2 * bflo(h2));
        atomicAdd(&accum[r2 * HID + 64 + lane], w2 * bfhi(h2));
        atomicAdd(&accum[r3 * HID + lane], w3 * bflo(h3));
        atomicAdd(&accum[r3 * HID + 64 + lane], w3 * bfhi(h3));
    }
    for (; i < cntb; i += 8) {
        int2 e0 = es[base + i];
        unsigned c0 = (unsigned)e0.x & 0x1FFFFu, r0 = (unsigned)e0.x >> 17;
        unsigned h0 = *(const unsigned*)&H[(size_t)c0 * HID + fo];
        float w0 = __int_as_float(e0.y);
        atomicAdd(&accum[r0 * HID + lane], w0 * bflo(h0));
        atomicAdd(&accum[r0 * HID + 64 + lane], w0 * bfhi(h0));
    }
    __syncthreads();

    int rmax = min(RPB, N - b * RPB);  // may be <= 0 for tail buckets
    // fused stats: feature f handled by thread f (<128)
    if (t < 128 && rmax > 0) {
        int slot = (t >> 1) + (t & 1) * 64;
        float s1 = 0.f, s2 = 0.f;
        for (int r = 0; r < rmax; ++r) {
            float v = accum[r * HID + slot];
            s1 += v;
            s2 += v * v;
        }
        int st = (b & 7) * 256;
        atomicAdd(&Spart[st + t], s1);
        atomicAdd(&Spart[st + 128 + t], s2);
    }
    // write M (un-permute slots; coalesced per 128-thread group)
    for (int idx = t; idx < rmax * HID; idx += 512) {
        int r = idx >> 7, f = idx & 127;
        int slot = (f >> 1) + (f & 1) * 64;
        M[(size_t)(b * RPB + r) * HID + f] = accum[r * HID + slot];
    }
}

// ---------------- column-wise stats for y (fp32, striped) ----------------
__global__ __launch_bounds__(256) void k_reduce(const float* __restrict__ X,
                                                float* __restrict__ S, int N) {
    __shared__ float sh1[HID], sh2[HID];
    int f = threadIdx.x & 127;
    int sub = threadIdx.x >> 7;
    float s1 = 0.f, s2 = 0.f;
    for (int r = blockIdx.x * 2 + sub; r < N; r += gridDim.x * 2) {
        float v = X[(size_t)r * HID + f];
        s1 += v;
        s2 += v * v;
    }
    if (sub == 1) { sh1[f] = s1; sh2[f] = s2; }
    __syncthreads();
    if (sub == 0) {
        int st = (blockIdx.x & 7) * 256;
        atomicAdd(&S[st + f], s1 + sh1[f]);
        atomicAdd(&S[st + 128 + f], s2 + sh2[f]);
    }
}

// A = gamma*rsqrt(var+eps); B = beta - A*alpha*mu (sums 8 stripes)
__global__ void k_finalize(const float* __restrict__ S, const float* __restrict__ gamma,
                           const float* __restrict__ beta, const float* __restrict__ alpha,
                           float* __restrict__ AB, float invN) {
    int f = threadIdx.x;
    float sum = 0.f, sq = 0.f;
#pragma unroll
    for (int c = 0; c < 8; ++c) {
        sum += S[c * 256 + f];
        sq += S[c * 256 + 128 + f];
    }
    float mu = sum * invN;
    float ex2 = sq * invN;
    float a = alpha[f];
    float var = ex2 - 2.f * a * mu * mu + a * a * mu * mu;
    float rs = rsqrtf(var + 1e-5f);
    float A = gamma[f] * rs;
    float B = beta[f] - A * a * mu;
    AB[f] = A;
    AB[HID + f] = B;
}

// ---------------------------------------------------------------------------
extern "C" void kernel_launch(void* const* d_in, const int* in_sizes, int n_in,
                              void* d_out, int out_size, void* d_ws, size_t ws_size,
                              hipStream_t stream) {
    const int*   x_idx = (const int*)d_in[0];
    const int*   ei    = (const int*)d_in[1];
    const float* ew    = (const float*)d_in[2];
    const float* emb   = (const float*)d_in[3];
    const float* Wt    = (const float*)d_in[4];
    const float* bt    = (const float*)d_in[5];
    const float* Wc    = (const float*)d_in[6];
    const float* bc    = (const float*)d_in[7];
    const float* cg_g  = (const float*)d_in[8];
    const float* cg_b  = (const float*)d_in[9];
    const float* cg_a  = (const float*)d_in[10];
    const float* gn_g  = (const float*)d_in[11];
    const float* gn_b  = (const float*)d_in[12];
    const float* gn_a  = (const float*)d_in[13];
    const int N = in_sizes[0];
    const int E = in_sizes[2];
    const int* row = ei;
    const int* col = ei + E;

    char* ws = (char*)d_ws;
    size_t off = 0;
    auto alloc = [&](size_t bytes) -> void* {
        size_t o = (off + 511) & ~(size_t)511;
        off = o + bytes;
        return (void*)(ws + o);
    };
    unsigned* cursor = (unsigned*)alloc(NB * 4);             // zeroed
    float*    Spart  = (float*)alloc(5 * 8 * 256 * 4);       // zeroed
    size_t zero_end = off;
    float*    AB      = (float*)alloc(5 * 256 * 4);
    unsigned short* WtT = (unsigned short*)alloc((size_t)3 * 128 * 128 * 2);
    unsigned short* WcT = (unsigned short*)alloc((size_t)3 * 128 * 256 * 2);
    int2*     binned  = (int2*)alloc((size_t)NB * CAPB * 8); // 33.6 MB
    unsigned short* H = (unsigned short*)alloc((size_t)N * HID * 2);
    float*    X       = (float*)alloc((size_t)N * HID * 4);
    float*    M       = (float*)alloc((size_t)N * HID * 4);
    if (off > ws_size) {
        fprintf(stderr, "kernel_launch: ws too small (%zu > %zu)\n", off, ws_size);
        return;
    }

    hipMemsetAsync(d_ws, 0, zero_end, stream);

    k_prepw<<<(3 * 128 * 128 + 3 * 256 * 128 + 255) / 256, 256, 0, stream>>>(Wt, Wc, WtT, WcT);
    k_binA<<<(E + TILE_A - 1) / TILE_A, 256, 0, stream>>>(row, col, ew, binned, cursor, E);
    k_binB<<<NB, 256, 0, stream>>>(binned, cursor);
    k_gather<<<(N * 32 + 255) / 256, 256, 0, stream>>>(x_idx, emb, X, N);

    int gemm_blocks = (N + GM_ROWS - 1) / GM_ROWS;
    auto gemm = [&](const float* X1, const float* AB1, int rl1,
                    const float* X2, const float* AB2, int rl2,
                    const unsigned short* Wn, int Kpitch, int nstage,
                    const float* bias, void* Y, int relu_out, int out_bf16) {
        k_gemm<<<gemm_blocks, 256, 0, stream>>>(X1, AB1, rl1, X2, AB2, rl2, Wn, Kpitch,
                                                nstage, bias, Y, relu_out, out_bf16, N);
    };
    auto agg = [&](int stage) {
        k_aggT<<<NB, 512, 0, stream>>>(H, binned, cursor, M, Spart + stage * 2048, N);
    };
    auto red = [&](const float* buf, int stage) {
        k_reduce<<<256, 256, 0, stream>>>(buf, Spart + stage * 2048, N);
    };
    auto fin = [&](int stage, const float* g, const float* b, const float* a) {
        k_finalize<<<1, 128, 0, stream>>>(Spart + stage * 2048, g, b, a, AB + stage * 256,
                                          1.0f / (float)N);
    };

    // ---- Layer 0 ----
    gemm(X, nullptr, 0, nullptr, nullptr, 0, WtT, 128, 1, bt, H, 1, 1);
    agg(0);
    fin(0, cg_g, cg_b, cg_a);
    gemm(M, AB + 0 * 256, 0, X, nullptr, 0, WcT, 256, 2, bc, X, 0, 0);  // y0 -> X (in-place)
    red(X, 1);
    fin(1, gn_g, gn_b, gn_a);

    // ---- Layer 1 ----  (x1 = relu(gn0(y0)) applied on load via AB1)
    gemm(X, AB + 1 * 256, 1, nullptr, nullptr, 0, WtT + 16384, 128, 1, bt + 128, H, 1, 1);
    agg(2);
    fin(2, cg_g + 128, cg_b + 128, cg_a + 128);
    gemm(M, AB + 2 * 256, 0, X, AB + 1 * 256, 1, WcT + 32768, 256, 2, bc + 128, X, 0, 0);
    red(X, 3);
    fin(3, gn_g + 128, gn_b + 128, gn_a + 128);

    // ---- Layer 2 ----  (x2 = relu(gn1(y1)) applied on load via AB3)
    gemm(X, AB + 3 * 256, 1, nullptr, nullptr, 0, WtT + 2 * 16384, 128, 1, bt + 256, H, 1, 1);
    agg(4);
    fin(4, cg_g + 256, cg_b + 256, cg_a + 256);
    gemm(M, AB + 4 * 256, 0, X, AB + 3 * 256, 1, WcT + 2 * 32768, 256, 2, bc + 256,
         d_out, 0, 0);
}

// Round 6
// 996.687 us; speedup vs baseline: 6.7988x; 6.7988x over previous
//
#include <hip/hip_runtime.h>
#include <cstdio>

// ---------------------------------------------------------------------------
// MyGCN: 3-layer GraphConv GCN on MI355X.
// Round 6: revert to the round-3 proven aggregation (wave-per-row CSR gather,
// bf16 H operand, fp32 M) after round-5's LDS-atomic experiment regressed 15x.
// Changes vs round 3:
//  - fp32 X/M/y precision kept from round 5 (absmax 0.0625)
//  - GraphNorm stats for M fused into k_agg (16 rows/wave, register stats ->
//    LDS combine -> 8-way striped global atomics): 3 k_reduce dispatches gone
//  - k_gather eliminated: k_gemm takes an optional row-index array and reads
//    emb[x_idx[row]] directly during LDS staging (emb is L3-resident)
// CSR build: round-2 bucketed two-pass (write amplification ~1).
// GEMMs: bf16 MFMA 16x16x32, GraphNorm folded to per-feature affine (A,B)
// applied during LDS staging.
// ---------------------------------------------------------------------------

#define HID 128

typedef __attribute__((ext_vector_type(8))) short short8;
typedef __attribute__((ext_vector_type(4))) float floatx4;

__device__ __forceinline__ unsigned short f2bf(float f) {
    unsigned u = __float_as_uint(f);
    unsigned r = (u + 0x7FFFu + ((u >> 16) & 1u)) >> 16;  // RNE
    return (unsigned short)r;
}
__device__ __forceinline__ float bflo(unsigned u) { return __uint_as_float(u << 16); }
__device__ __forceinline__ float bfhi(unsigned u) { return __uint_as_float(u & 0xFFFF0000u); }

// ---------------- bucketed CSR build (round-2 proven) ----------------
#define NB 512      // buckets
#define RPB 196     // rows per bucket (512*196 = 100352 >= N)
#define CAPB 8192   // edges capacity per bucket (mean 6272 + 24 sigma)
#define TILE_A 2048 // edges per block in pass A

__global__ __launch_bounds__(256) void k_binA(
    const int* __restrict__ row, const int* __restrict__ col,
    const float* __restrict__ ew, int2* __restrict__ binned,
    unsigned* __restrict__ cursor, int E) {
    __shared__ int2 stag[TILE_A];
    __shared__ unsigned short bof[TILE_A];
    __shared__ unsigned hist[NB], scanned[NB], bump[NB];
    __shared__ int delta[NB];
    __shared__ unsigned scanw[256];
    int t = threadIdx.x;
    int tileBase = blockIdx.x * TILE_A;
    int tcnt = min(TILE_A, E - tileBase);

    hist[t] = 0; hist[t + 256] = 0;
    __syncthreads();

    int myb[8]; int2 myv[8];
#pragma unroll
    for (int i = 0; i < 8; ++i) {
        int idx = t + i * 256;
        if (idx < tcnt) {
            int e = tileBase + idx;
            int r = row[e];
            int c = col[e];
            float w = ew[e];
            int b = r / RPB;
            int rl = r - b * RPB;
            myb[i] = b;
            myv[i] = make_int2((rl << 17) | c, __float_as_int(w));
            atomicAdd(&hist[b], 1u);
        } else {
            myb[i] = -1;
            myv[i] = make_int2(0, 0);
        }
    }
    __syncthreads();

    unsigned h0 = hist[2 * t], h1 = hist[2 * t + 1];
    unsigned p = h0 + h1;
    scanw[t] = p;
    __syncthreads();
    for (int o = 1; o < 256; o <<= 1) {
        unsigned x = (t >= o) ? scanw[t - o] : 0u;
        __syncthreads();
        scanw[t] += x;
        __syncthreads();
    }
    unsigned excl = scanw[t] - p;
    scanned[2 * t] = excl;          bump[2 * t] = excl;
    scanned[2 * t + 1] = excl + h0; bump[2 * t + 1] = excl + h0;
    __syncthreads();

#pragma unroll
    for (int j = 0; j < 2; ++j) {
        int b = t + j * 256;
        unsigned c = hist[b];
        if (c) {
            unsigned old = atomicAdd(&cursor[b], c);
            delta[b] = (int)((unsigned)b * CAPB + old) - (int)scanned[b];
        }
    }
    __syncthreads();

#pragma unroll
    for (int i = 0; i < 8; ++i) {
        if (myb[i] >= 0) {
            unsigned s = atomicAdd(&bump[myb[i]], 1u);
            stag[s] = myv[i];
            bof[s] = (unsigned short)myb[i];
        }
    }
    __syncthreads();

    for (int i = t; i < tcnt; i += 256) {
        int b = bof[i];
        int dst = delta[b] + i;
        if (dst < (b + 1) * CAPB) binned[dst] = stag[i];
    }
}

__global__ void k_bscan(const unsigned* __restrict__ cursor, unsigned* __restrict__ outbase) {
    __shared__ unsigned scanw[256];
    int t = threadIdx.x;
    unsigned h0 = min(cursor[2 * t], (unsigned)CAPB);
    unsigned h1 = min(cursor[2 * t + 1], (unsigned)CAPB);
    unsigned p = h0 + h1;
    scanw[t] = p;
    __syncthreads();
    for (int o = 1; o < 256; o <<= 1) {
        unsigned x = (t >= o) ? scanw[t - o] : 0u;
        __syncthreads();
        scanw[t] += x;
        __syncthreads();
    }
    unsigned excl = scanw[t] - p;
    outbase[2 * t] = excl;
    outbase[2 * t + 1] = excl + h0;
}

__global__ __launch_bounds__(256) void k_binB(
    const int2* __restrict__ binned, const unsigned* __restrict__ cursor,
    const unsigned* __restrict__ outbase, int2* __restrict__ edge_s,
    unsigned* __restrict__ endp, unsigned* __restrict__ cntg, int N) {
    __shared__ unsigned hist[256], bump[256], scanw[256];
    __shared__ float wsum[256], inv[256];
    int b = blockIdx.x, t = threadIdx.x;
    size_t base_in = (size_t)b * CAPB;
    unsigned cntb = min(cursor[b], (unsigned)CAPB);
    unsigned outb = outbase[b];

    hist[t] = 0;
    wsum[t] = 0.f;
    __syncthreads();
    for (unsigned i = t; i < cntb; i += 256) {
        int2 v = binned[base_in + i];
        unsigned rl = ((unsigned)v.x) >> 17;
        atomicAdd(&hist[rl], 1u);
        atomicAdd(&wsum[rl], __int_as_float(v.y));
    }
    __syncthreads();

    unsigned h = hist[t];
    scanw[t] = h;
    __syncthreads();
    for (int o = 1; o < 256; o <<= 1) {
        unsigned x = (t >= o) ? scanw[t - o] : 0u;
        __syncthreads();
        scanw[t] += x;
        __syncthreads();
    }
    unsigned excl = scanw[t] - h;
    bump[t] = excl;
    float d = wsum[t];
    d = (d < 0.5f) ? d + 1.0f : d;
    inv[t] = 1.0f / d;
    int grow = b * RPB + t;
    if (t < RPB && grow < N) {
        endp[grow] = outb + excl + h;
        cntg[grow] = h;
    }
    __syncthreads();

    for (unsigned i = t; i < cntb; i += 256) {
        int2 v = binned[base_in + i];
        unsigned rl = ((unsigned)v.x) >> 17;
        unsigned pos = outb + atomicAdd(&bump[rl], 1u);
        float w = __int_as_float(v.y) * inv[rl];
        edge_s[pos] = make_int2(v.x & 0x1FFFF, __float_as_int(w));
    }
}

// ---------------- weight prep: transpose + bf16 ----------------
__global__ void k_prepw(const float* __restrict__ Wt, const float* __restrict__ Wc,
                        unsigned short* __restrict__ WtT, unsigned short* __restrict__ WcT) {
    int tid = blockIdx.x * blockDim.x + threadIdx.x;
    const int T1 = 3 * 128 * 128;
    const int T2 = 3 * 256 * 128;
    if (tid < T1) {
        int l = tid >> 14, rem = tid & 16383;
        int n = rem >> 7, k = rem & 127;
        WtT[tid] = f2bf(Wt[l * 16384 + k * 128 + n]);
    } else if (tid < T1 + T2) {
        int t2 = tid - T1;
        int l = t2 >> 15, rem = t2 & 32767;
        int n = rem >> 8, k = rem & 255;
        WcT[t2] = f2bf(Wc[l * 32768 + k * 128 + n]);
    }
}

// ---------------- bf16 MFMA GEMM ----------------
// Stage inputs are fp32; optional per-stage row-index array Gi (for direct
// embedding gather: row srow = Gi[grow]); optional per-feature affine AB(+relu).
#define GM_ROWS 128
#define LDSP 136

__global__ __launch_bounds__(256) void k_gemm(
    const float* __restrict__ X1, const int* __restrict__ G1,
    const float* __restrict__ AB1, int relu1,
    const float* __restrict__ X2, const int* __restrict__ G2,
    const float* __restrict__ AB2, int relu2,
    const unsigned short* __restrict__ Wn, int Kpitch, int nstage,
    const float* __restrict__ bias, void* __restrict__ Y, int relu_out, int out_bf16,
    int N) {
    __shared__ unsigned short Ws[128 * LDSP];
    __shared__ unsigned short Xs[128 * LDSP];
    int t = threadIdx.x;
    int rowBase = blockIdx.x * GM_ROWS;
    int lane = t & 63, wave = t >> 6;
    int quad = lane >> 4, l16 = lane & 15;

    floatx4 acc[2][8];
#pragma unroll
    for (int i = 0; i < 2; ++i)
#pragma unroll
        for (int j = 0; j < 8; ++j) acc[i][j] = (floatx4){0.f, 0.f, 0.f, 0.f};

    int kg = (t & 15) * 8;
    int r0 = t >> 4;

    for (int s = 0; s < nstage; ++s) {
        const float* Xp = s ? X2 : X1;
        const int* Gp = s ? G2 : G1;
        const float* ABp = s ? AB2 : AB1;
        int rl = s ? relu2 : relu1;
        int koff = s * 128;

#pragma unroll
        for (int j = 0; j < 8; ++j) {
            int n = r0 + 16 * j;
            *(short8*)&Ws[n * LDSP + kg] =
                *(const short8*)&Wn[(size_t)n * Kpitch + koff + kg];
        }
        floatx4 Av0 = {1.f, 1.f, 1.f, 1.f}, Av1 = Av0;
        floatx4 Bv0 = {0.f, 0.f, 0.f, 0.f}, Bv1 = Bv0;
        if (ABp) {
            Av0 = *(const floatx4*)&ABp[kg];
            Av1 = *(const floatx4*)&ABp[kg + 4];
            Bv0 = *(const floatx4*)&ABp[HID + kg];
            Bv1 = *(const floatx4*)&ABp[HID + kg + 4];
        }
#pragma unroll
        for (int j = 0; j < 8; ++j) {
            int r = r0 + 16 * j;
            int grow = rowBase + r;
            floatx4 x0 = {0.f, 0.f, 0.f, 0.f}, x1 = x0;
            if (grow < N) {
                size_t srow = Gp ? (size_t)Gp[grow] : (size_t)grow;
                x0 = *(const floatx4*)&Xp[srow * HID + kg];
                x1 = *(const floatx4*)&Xp[srow * HID + kg + 4];
            }
            if (ABp) {
#pragma unroll
                for (int c = 0; c < 4; ++c) {
                    x0[c] = fmaf(x0[c], Av0[c], Bv0[c]);
                    x1[c] = fmaf(x1[c], Av1[c], Bv1[c]);
                }
                if (rl) {
#pragma unroll
                    for (int c = 0; c < 4; ++c) {
                        x0[c] = fmaxf(x0[c], 0.f);
                        x1[c] = fmaxf(x1[c], 0.f);
                    }
                }
            }
            short8 st;
            st[0] = (short)f2bf(x0[0]); st[1] = (short)f2bf(x0[1]);
            st[2] = (short)f2bf(x0[2]); st[3] = (short)f2bf(x0[3]);
            st[4] = (short)f2bf(x1[0]); st[5] = (short)f2bf(x1[1]);
            st[6] = (short)f2bf(x1[2]); st[7] = (short)f2bf(x1[3]);
            *(short8*)&Xs[r * LDSP + kg] = st;
        }
        __syncthreads();

#pragma unroll
        for (int ks = 0; ks < 4; ++ks) {
            int kb = ks * 32 + quad * 8;
            short8 a0 = *(const short8*)&Xs[(wave * 32 + l16) * LDSP + kb];
            short8 a1 = *(const short8*)&Xs[(wave * 32 + 16 + l16) * LDSP + kb];
#pragma unroll
            for (int ni = 0; ni < 8; ++ni) {
                short8 b = *(const short8*)&Ws[(ni * 16 + l16) * LDSP + kb];
                acc[0][ni] = __builtin_amdgcn_mfma_f32_16x16x32_bf16(a0, b, acc[0][ni], 0, 0, 0);
                acc[1][ni] = __builtin_amdgcn_mfma_f32_16x16x32_bf16(a1, b, acc[1][ni], 0, 0, 0);
            }
        }
        __syncthreads();
    }

#pragma unroll
    for (int mi = 0; mi < 2; ++mi) {
#pragma unroll
        for (int ni = 0; ni < 8; ++ni) {
            int gcol = ni * 16 + l16;
            float bv = bias[gcol];
#pragma unroll
            for (int reg = 0; reg < 4; ++reg) {
                int grow = rowBase + wave * 32 + mi * 16 + quad * 4 + reg;
                if (grow < N) {
                    float v = acc[mi][ni][reg] + bv;
                    if (relu_out) v = fmaxf(v, 0.f);
                    if (out_bf16)
                        ((unsigned short*)Y)[(size_t)grow * HID + gcol] = f2bf(v);
                    else
                        ((float*)Y)[(size_t)grow * HID + gcol] = v;
                }
            }
        }
    }
}

// ---------------- aggregation + fused GraphNorm stats ----------------
// Round-3 structure: one wave per row (64 lanes x 2 feats), bf16 H gather,
// CSR segments, no atomics on M. Each wave handles AGG_R rows sequentially,
// accumulating per-feature stats in registers; block combines via LDS and
// issues 256 striped global atomics.
#define AGG_R 16  // rows per wave -> 64 rows per block

__global__ __launch_bounds__(256) void k_agg(
    const unsigned short* __restrict__ H, const int2* __restrict__ es,
    const unsigned* __restrict__ endp, const unsigned* __restrict__ cnt,
    float* __restrict__ M, float* __restrict__ Spart, int N) {
    __shared__ float sb[4][256];
    int t = threadIdx.x;
    int wv = t >> 6, lane = t & 63;
    int fo = lane * 2;
    int rowBase = blockIdx.x * (4 * AGG_R) + wv * AGG_R;
    float s1a = 0.f, s1b = 0.f, s2a = 0.f, s2b = 0.f;

    for (int j = 0; j < AGG_R; ++j) {
        int rowi = rowBase + j;
        if (rowi >= N) break;
        unsigned e = endp[rowi];
        unsigned p = e - cnt[rowi];
        float a0 = 0.f, a1 = 0.f;
        for (; p + 3 < e; p += 4) {
            int2 e0 = es[p], e1 = es[p + 1], e2 = es[p + 2], e3 = es[p + 3];
            unsigned h0 = *(const unsigned*)&H[(size_t)e0.x * HID + fo];
            unsigned h1 = *(const unsigned*)&H[(size_t)e1.x * HID + fo];
            unsigned h2 = *(const unsigned*)&H[(size_t)e2.x * HID + fo];
            unsigned h3 = *(const unsigned*)&H[(size_t)e3.x * HID + fo];
            float w0 = __int_as_float(e0.y), w1 = __int_as_float(e1.y);
            float w2 = __int_as_float(e2.y), w3 = __int_as_float(e3.y);
            a0 = fmaf(w0, bflo(h0), a0); a1 = fmaf(w0, bfhi(h0), a1);
            a0 = fmaf(w1, bflo(h1), a0); a1 = fmaf(w1, bfhi(h1), a1);
            a0 = fmaf(w2, bflo(h2), a0); a1 = fmaf(w2, bfhi(h2), a1);
            a0 = fmaf(w3, bflo(h3), a0); a1 = fmaf(w3, bfhi(h3), a1);
        }
        for (; p < e; ++p) {
            int2 e0 = es[p];
            unsigned h0 = *(const unsigned*)&H[(size_t)e0.x * HID + fo];
            float w0 = __int_as_float(e0.y);
            a0 = fmaf(w0, bflo(h0), a0); a1 = fmaf(w0, bfhi(h0), a1);
        }
        s1a += a0; s1b += a1;
        s2a += a0 * a0; s2b += a1 * a1;
        *(float2*)&M[(size_t)rowi * HID + fo] = make_float2(a0, a1);
    }

    sb[wv][fo] = s1a;
    sb[wv][fo + 1] = s1b;
    sb[wv][128 + fo] = s2a;
    sb[wv][128 + fo + 1] = s2b;
    __syncthreads();
    {
        float v = sb[0][t] + sb[1][t] + sb[2][t] + sb[3][t];
        atomicAdd(&Spart[(blockIdx.x & 7) * 256 + t], v);
    }
}

// ---------------- column-wise stats for y (fp32, striped) ----------------
__global__ __launch_bounds__(256) void k_reduce(const float* __restrict__ X,
                                                float* __restrict__ S, int N) {
    __shared__ float sh1[HID], sh2[HID];
    int f = threadIdx.x & 127;
    int sub = threadIdx.x >> 7;
    float s1 = 0.f, s2 = 0.f;
    for (int r = blockIdx.x * 2 + sub; r < N; r += gridDim.x * 2) {
        float v = X[(size_t)r * HID + f];
        s1 += v;
        s2 += v * v;
    }
    if (sub == 1) { sh1[f] = s1; sh2[f] = s2; }
    __syncthreads();
    if (sub == 0) {
        int st = (blockIdx.x & 7) * 256;
        atomicAdd(&S[st + f], s1 + sh1[f]);
        atomicAdd(&S[st + 128 + f], s2 + sh2[f]);
    }
}

// A = gamma*rsqrt(var+eps); B = beta - A*alpha*mu (sums 8 stripes)
__global__ void k_finalize(const float* __restrict__ S, const float* __restrict__ gamma,
                           const float* __restrict__ beta, const float* __restrict__ alpha,
                           float* __restrict__ AB, float invN) {
    int f = threadIdx.x;
    float sum = 0.f, sq = 0.f;
#pragma unroll
    for (int c = 0; c < 8; ++c) {
        sum += S[c * 256 + f];
        sq += S[c * 256 + 128 + f];
    }
    float mu = sum * invN;
    float ex2 = sq * invN;
    float a = alpha[f];
    float var = ex2 - 2.f * a * mu * mu + a * a * mu * mu;
    float rs = rsqrtf(var + 1e-5f);
    float A = gamma[f] * rs;
    float B = beta[f] - A * a * mu;
    AB[f] = A;
    AB[HID + f] = B;
}

// ---------------------------------------------------------------------------
extern "C" void kernel_launch(void* const* d_in, const int* in_sizes, int n_in,
                              void* d_out, int out_size, void* d_ws, size_t ws_size,
                              hipStream_t stream) {
    const int*   x_idx = (const int*)d_in[0];
    const int*   ei    = (const int*)d_in[1];
    const float* ew    = (const float*)d_in[2];
    const float* emb   = (const float*)d_in[3];
    const float* Wt    = (const float*)d_in[4];
    const float* bt    = (const float*)d_in[5];
    const float* Wc    = (const float*)d_in[6];
    const float* bc    = (const float*)d_in[7];
    const float* cg_g  = (const float*)d_in[8];
    const float* cg_b  = (const float*)d_in[9];
    const float* cg_a  = (const float*)d_in[10];
    const float* gn_g  = (const float*)d_in[11];
    const float* gn_b  = (const float*)d_in[12];
    const float* gn_a  = (const float*)d_in[13];
    const int N = in_sizes[0];
    const int E = in_sizes[2];
    const int* row = ei;
    const int* col = ei + E;

    char* ws = (char*)d_ws;
    size_t off = 0;
    auto alloc = [&](size_t bytes) -> void* {
        size_t o = (off + 511) & ~(size_t)511;
        off = o + bytes;
        return (void*)(ws + o);
    };
    unsigned* cursor = (unsigned*)alloc(NB * 4);             // zeroed
    float*    Spart  = (float*)alloc(5 * 8 * 256 * 4);       // zeroed
    size_t zero_end = off;
    unsigned* outbase = (unsigned*)alloc(NB * 4);
    unsigned* endp    = (unsigned*)alloc((size_t)N * 4);
    unsigned* cnt     = (unsigned*)alloc((size_t)N * 4);
    float*    AB      = (float*)alloc(5 * 256 * 4);
    unsigned short* WtT = (unsigned short*)alloc((size_t)3 * 128 * 128 * 2);
    unsigned short* WcT = (unsigned short*)alloc((size_t)3 * 128 * 256 * 2);
    int2*     binned  = (int2*)alloc((size_t)NB * CAPB * 8); // 33.6 MB
    int2*     edge_s  = (int2*)alloc((size_t)E * 8);         // 25.6 MB
    unsigned short* H = (unsigned short*)alloc((size_t)N * HID * 2);
    float*    X       = (float*)alloc((size_t)N * HID * 4);
    float*    M       = (float*)alloc((size_t)N * HID * 4);
    if (off > ws_size) {
        fprintf(stderr, "kernel_launch: ws too small (%zu > %zu)\n", off, ws_size);
        return;
    }

    hipMemsetAsync(d_ws, 0, zero_end, stream);

    k_prepw<<<(3 * 128 * 128 + 3 * 256 * 128 + 255) / 256, 256, 0, stream>>>(Wt, Wc, WtT, WcT);
    k_binA<<<(E + TILE_A - 1) / TILE_A, 256, 0, stream>>>(row, col, ew, binned, cursor, E);
    k_bscan<<<1, 256, 0, stream>>>(cursor, outbase);
    k_binB<<<NB, 256, 0, stream>>>(binned, cursor, outbase, edge_s, endp, cnt, N);

    int gemm_blocks = (N + GM_ROWS - 1) / GM_ROWS;
    auto gemm = [&](const float* X1, const int* G1, const float* AB1, int rl1,
                    const float* X2, const int* G2, const float* AB2, int rl2,
                    const unsigned short* Wn, int Kpitch, int nstage,
                    const float* bias, void* Y, int relu_out, int out_bf16) {
        k_gemm<<<gemm_blocks, 256, 0, stream>>>(X1, G1, AB1, rl1, X2, G2, AB2, rl2,
                                                Wn, Kpitch, nstage, bias, Y,
                                                relu_out, out_bf16, N);
    };
    int aggB = (N + 4 * AGG_R - 1) / (4 * AGG_R);
    auto agg = [&](int stage) {
        k_agg<<<aggB, 256, 0, stream>>>(H, edge_s, endp, cnt, M, Spart + stage * 2048, N);
    };
    auto red = [&](const float* buf, int stage) {
        k_reduce<<<256, 256, 0, stream>>>(buf, Spart + stage * 2048, N);
    };
    auto fin = [&](int stage, const float* g, const float* b, const float* a) {
        k_finalize<<<1, 128, 0, stream>>>(Spart + stage * 2048, g, b, a, AB + stage * 256,
                                          1.0f / (float)N);
    };

    // ---- Layer 0 ----  (x0 = emb[x_idx], gathered in-staging)
    gemm(emb, x_idx, nullptr, 0, nullptr, nullptr, nullptr, 0, WtT, 128, 1, bt, H, 1, 1);
    agg(0);
    fin(0, cg_g, cg_b, cg_a);
    gemm(M, nullptr, AB + 0 * 256, 0, emb, x_idx, nullptr, 0, WcT, 256, 2, bc, X, 0, 0);
    red(X, 1);
    fin(1, gn_g, gn_b, gn_a);

    // ---- Layer 1 ----  (x1 = relu(gn0(y0)) applied on load via AB1)
    gemm(X, nullptr, AB + 1 * 256, 1, nullptr, nullptr, nullptr, 0,
         WtT + 16384, 128, 1, bt + 128, H, 1, 1);
    agg(2);
    fin(2, cg_g + 128, cg_b + 128, cg_a + 128);
    gemm(M, nullptr, AB + 2 * 256, 0, X, nullptr, AB + 1 * 256, 1,
         WcT + 32768, 256, 2, bc + 128, X, 0, 0);
    red(X, 3);
    fin(3, gn_g + 128, gn_b + 128, gn_a + 128);

    // ---- Layer 2 ----  (x2 = relu(gn1(y1)) applied on load via AB3)
    gemm(X, nullptr, AB + 3 * 256, 1, nullptr, nullptr, nullptr, 0,
         WtT + 2 * 16384, 128, 1, bt + 256, H, 1, 1);
    agg(4);
    fin(4, cg_g + 256, cg_b + 256, cg_a + 256);
    gemm(M, nullptr, AB + 4 * 256, 0, X, nullptr, AB + 3 * 256, 1,
         WcT + 2 * 32768, 256, 2, bc + 256, d_out, 0, 0);
}

// Round 7
// 860.596 us; speedup vs baseline: 7.8739x; 1.1581x over previous
//
#include <hip/hip_runtime.h>
#include <cstdio>

// ---------------------------------------------------------------------------
// MyGCN: 3-layer GraphConv GCN on MI355X.
// Round 7 (consolidation on round-6):
//  - k_agg: AGG_R 16->4 (6250 blocks; round-3's occupancy) + 8-deep gather
//    unroll; fused M GraphNorm stats kept (16-way striped atomics)
//  - y GraphNorm stats fused into the concat-GEMM epilogue (y in registers;
//    shfl -> LDS -> striped atomics); k_reduce eliminated
//  - layer-0 embedding gather stays fused into GEMM staging (emb L3-resident)
// CSR build: round-2 bucketed two-pass. GEMMs: bf16 MFMA 16x16x32 with
// GraphNorm folded to per-feature affine (A,B) applied during LDS staging.
// ---------------------------------------------------------------------------

#define HID 128

typedef __attribute__((ext_vector_type(8))) short short8;
typedef __attribute__((ext_vector_type(4))) float floatx4;

__device__ __forceinline__ unsigned short f2bf(float f) {
    unsigned u = __float_as_uint(f);
    unsigned r = (u + 0x7FFFu + ((u >> 16) & 1u)) >> 16;  // RNE
    return (unsigned short)r;
}
__device__ __forceinline__ float bflo(unsigned u) { return __uint_as_float(u << 16); }
__device__ __forceinline__ float bfhi(unsigned u) { return __uint_as_float(u & 0xFFFF0000u); }

// ---------------- bucketed CSR build (round-2 proven) ----------------
#define NB 512      // buckets
#define RPB 196     // rows per bucket (512*196 = 100352 >= N)
#define CAPB 8192   // edges capacity per bucket
#define TILE_A 2048 // edges per block in pass A

__global__ __launch_bounds__(256) void k_binA(
    const int* __restrict__ row, const int* __restrict__ col,
    const float* __restrict__ ew, int2* __restrict__ binned,
    unsigned* __restrict__ cursor, int E) {
    __shared__ int2 stag[TILE_A];
    __shared__ unsigned short bof[TILE_A];
    __shared__ unsigned hist[NB], scanned[NB], bump[NB];
    __shared__ int delta[NB];
    __shared__ unsigned scanw[256];
    int t = threadIdx.x;
    int tileBase = blockIdx.x * TILE_A;
    int tcnt = min(TILE_A, E - tileBase);

    hist[t] = 0; hist[t + 256] = 0;
    __syncthreads();

    int myb[8]; int2 myv[8];
#pragma unroll
    for (int i = 0; i < 8; ++i) {
        int idx = t + i * 256;
        if (idx < tcnt) {
            int e = tileBase + idx;
            int r = row[e];
            int c = col[e];
            float w = ew[e];
            int b = r / RPB;
            int rl = r - b * RPB;
            myb[i] = b;
            myv[i] = make_int2((rl << 17) | c, __float_as_int(w));
            atomicAdd(&hist[b], 1u);
        } else {
            myb[i] = -1;
            myv[i] = make_int2(0, 0);
        }
    }
    __syncthreads();

    unsigned h0 = hist[2 * t], h1 = hist[2 * t + 1];
    unsigned p = h0 + h1;
    scanw[t] = p;
    __syncthreads();
    for (int o = 1; o < 256; o <<= 1) {
        unsigned x = (t >= o) ? scanw[t - o] : 0u;
        __syncthreads();
        scanw[t] += x;
        __syncthreads();
    }
    unsigned excl = scanw[t] - p;
    scanned[2 * t] = excl;          bump[2 * t] = excl;
    scanned[2 * t + 1] = excl + h0; bump[2 * t + 1] = excl + h0;
    __syncthreads();

#pragma unroll
    for (int j = 0; j < 2; ++j) {
        int b = t + j * 256;
        unsigned c = hist[b];
        if (c) {
            unsigned old = atomicAdd(&cursor[b], c);
            delta[b] = (int)((unsigned)b * CAPB + old) - (int)scanned[b];
        }
    }
    __syncthreads();

#pragma unroll
    for (int i = 0; i < 8; ++i) {
        if (myb[i] >= 0) {
            unsigned s = atomicAdd(&bump[myb[i]], 1u);
            stag[s] = myv[i];
            bof[s] = (unsigned short)myb[i];
        }
    }
    __syncthreads();

    for (int i = t; i < tcnt; i += 256) {
        int b = bof[i];
        int dst = delta[b] + i;
        if (dst < (b + 1) * CAPB) binned[dst] = stag[i];
    }
}

__global__ void k_bscan(const unsigned* __restrict__ cursor, unsigned* __restrict__ outbase) {
    __shared__ unsigned scanw[256];
    int t = threadIdx.x;
    unsigned h0 = min(cursor[2 * t], (unsigned)CAPB);
    unsigned h1 = min(cursor[2 * t + 1], (unsigned)CAPB);
    unsigned p = h0 + h1;
    scanw[t] = p;
    __syncthreads();
    for (int o = 1; o < 256; o <<= 1) {
        unsigned x = (t >= o) ? scanw[t - o] : 0u;
        __syncthreads();
        scanw[t] += x;
        __syncthreads();
    }
    unsigned excl = scanw[t] - p;
    outbase[2 * t] = excl;
    outbase[2 * t + 1] = excl + h0;
}

__global__ __launch_bounds__(256) void k_binB(
    const int2* __restrict__ binned, const unsigned* __restrict__ cursor,
    const unsigned* __restrict__ outbase, int2* __restrict__ edge_s,
    unsigned* __restrict__ endp, unsigned* __restrict__ cntg, int N) {
    __shared__ unsigned hist[256], bump[256], scanw[256];
    __shared__ float wsum[256], inv[256];
    int b = blockIdx.x, t = threadIdx.x;
    size_t base_in = (size_t)b * CAPB;
    unsigned cntb = min(cursor[b], (unsigned)CAPB);
    unsigned outb = outbase[b];

    hist[t] = 0;
    wsum[t] = 0.f;
    __syncthreads();
    for (unsigned i = t; i < cntb; i += 256) {
        int2 v = binned[base_in + i];
        unsigned rl = ((unsigned)v.x) >> 17;
        atomicAdd(&hist[rl], 1u);
        atomicAdd(&wsum[rl], __int_as_float(v.y));
    }
    __syncthreads();

    unsigned h = hist[t];
    scanw[t] = h;
    __syncthreads();
    for (int o = 1; o < 256; o <<= 1) {
        unsigned x = (t >= o) ? scanw[t - o] : 0u;
        __syncthreads();
        scanw[t] += x;
        __syncthreads();
    }
    unsigned excl = scanw[t] - h;
    bump[t] = excl;
    float d = wsum[t];
    d = (d < 0.5f) ? d + 1.0f : d;
    inv[t] = 1.0f / d;
    int grow = b * RPB + t;
    if (t < RPB && grow < N) {
        endp[grow] = outb + excl + h;
        cntg[grow] = h;
    }
    __syncthreads();

    for (unsigned i = t; i < cntb; i += 256) {
        int2 v = binned[base_in + i];
        unsigned rl = ((unsigned)v.x) >> 17;
        unsigned pos = outb + atomicAdd(&bump[rl], 1u);
        float w = __int_as_float(v.y) * inv[rl];
        edge_s[pos] = make_int2(v.x & 0x1FFFF, __float_as_int(w));
    }
}

// ---------------- weight prep: transpose + bf16 ----------------
__global__ void k_prepw(const float* __restrict__ Wt, const float* __restrict__ Wc,
                        unsigned short* __restrict__ WtT, unsigned short* __restrict__ WcT) {
    int tid = blockIdx.x * blockDim.x + threadIdx.x;
    const int T1 = 3 * 128 * 128;
    const int T2 = 3 * 256 * 128;
    if (tid < T1) {
        int l = tid >> 14, rem = tid & 16383;
        int n = rem >> 7, k = rem & 127;
        WtT[tid] = f2bf(Wt[l * 16384 + k * 128 + n]);
    } else if (tid < T1 + T2) {
        int t2 = tid - T1;
        int l = t2 >> 15, rem = t2 & 32767;
        int n = rem >> 8, k = rem & 255;
        WcT[t2] = f2bf(Wc[l * 32768 + k * 128 + n]);
    }
}

// ---------------- bf16 MFMA GEMM + optional fused column stats ----------------
// Stage inputs fp32; optional row-index array Gi (embedding gather); optional
// per-feature affine AB(+relu). If Sout != nullptr, per-column sum/sumsq of
// the (pre-relu_out) output are atomically accumulated (16-way striped).
#define GM_ROWS 128
#define LDSP 136

__global__ __launch_bounds__(256) void k_gemm(
    const float* __restrict__ X1, const int* __restrict__ G1,
    const float* __restrict__ AB1, int relu1,
    const float* __restrict__ X2, const int* __restrict__ G2,
    const float* __restrict__ AB2, int relu2,
    const unsigned short* __restrict__ Wn, int Kpitch, int nstage,
    const float* __restrict__ bias, void* __restrict__ Y, int relu_out, int out_bf16,
    float* __restrict__ Sout, int N) {
    __shared__ unsigned short Ws[128 * LDSP];
    __shared__ unsigned short Xs[128 * LDSP];
    __shared__ float sred[4][256];
    int t = threadIdx.x;
    int rowBase = blockIdx.x * GM_ROWS;
    int lane = t & 63, wave = t >> 6;
    int quad = lane >> 4, l16 = lane & 15;

    floatx4 acc[2][8];
#pragma unroll
    for (int i = 0; i < 2; ++i)
#pragma unroll
        for (int j = 0; j < 8; ++j) acc[i][j] = (floatx4){0.f, 0.f, 0.f, 0.f};

    int kg = (t & 15) * 8;
    int r0 = t >> 4;

    for (int s = 0; s < nstage; ++s) {
        const float* Xp = s ? X2 : X1;
        const int* Gp = s ? G2 : G1;
        const float* ABp = s ? AB2 : AB1;
        int rl = s ? relu2 : relu1;
        int koff = s * 128;

#pragma unroll
        for (int j = 0; j < 8; ++j) {
            int n = r0 + 16 * j;
            *(short8*)&Ws[n * LDSP + kg] =
                *(const short8*)&Wn[(size_t)n * Kpitch + koff + kg];
        }
        floatx4 Av0 = {1.f, 1.f, 1.f, 1.f}, Av1 = Av0;
        floatx4 Bv0 = {0.f, 0.f, 0.f, 0.f}, Bv1 = Bv0;
        if (ABp) {
            Av0 = *(const floatx4*)&ABp[kg];
            Av1 = *(const floatx4*)&ABp[kg + 4];
            Bv0 = *(const floatx4*)&ABp[HID + kg];
            Bv1 = *(const floatx4*)&ABp[HID + kg + 4];
        }
#pragma unroll
        for (int j = 0; j < 8; ++j) {
            int r = r0 + 16 * j;
            int grow = rowBase + r;
            floatx4 x0 = {0.f, 0.f, 0.f, 0.f}, x1 = x0;
            if (grow < N) {
                size_t srow = Gp ? (size_t)Gp[grow] : (size_t)grow;
                x0 = *(const floatx4*)&Xp[srow * HID + kg];
                x1 = *(const floatx4*)&Xp[srow * HID + kg + 4];
            }
            if (ABp) {
#pragma unroll
                for (int c = 0; c < 4; ++c) {
                    x0[c] = fmaf(x0[c], Av0[c], Bv0[c]);
                    x1[c] = fmaf(x1[c], Av1[c], Bv1[c]);
                }
                if (rl) {
#pragma unroll
                    for (int c = 0; c < 4; ++c) {
                        x0[c] = fmaxf(x0[c], 0.f);
                        x1[c] = fmaxf(x1[c], 0.f);
                    }
                }
            }
            short8 st;
            st[0] = (short)f2bf(x0[0]); st[1] = (short)f2bf(x0[1]);
            st[2] = (short)f2bf(x0[2]); st[3] = (short)f2bf(x0[3]);
            st[4] = (short)f2bf(x1[0]); st[5] = (short)f2bf(x1[1]);
            st[6] = (short)f2bf(x1[2]); st[7] = (short)f2bf(x1[3]);
            *(short8*)&Xs[r * LDSP + kg] = st;
        }
        __syncthreads();

#pragma unroll
        for (int ks = 0; ks < 4; ++ks) {
            int kb = ks * 32 + quad * 8;
            short8 a0 = *(const short8*)&Xs[(wave * 32 + l16) * LDSP + kb];
            short8 a1 = *(const short8*)&Xs[(wave * 32 + 16 + l16) * LDSP + kb];
#pragma unroll
            for (int ni = 0; ni < 8; ++ni) {
                short8 b = *(const short8*)&Ws[(ni * 16 + l16) * LDSP + kb];
                acc[0][ni] = __builtin_amdgcn_mfma_f32_16x16x32_bf16(a0, b, acc[0][ni], 0, 0, 0);
                acc[1][ni] = __builtin_amdgcn_mfma_f32_16x16x32_bf16(a1, b, acc[1][ni], 0, 0, 0);
            }
        }
        __syncthreads();
    }

    float s1[8], s2[8];
#pragma unroll
    for (int ni = 0; ni < 8; ++ni) { s1[ni] = 0.f; s2[ni] = 0.f; }

#pragma unroll
    for (int mi = 0; mi < 2; ++mi) {
#pragma unroll
        for (int ni = 0; ni < 8; ++ni) {
            int gcol = ni * 16 + l16;
            float bv = bias[gcol];
#pragma unroll
            for (int reg = 0; reg < 4; ++reg) {
                int grow = rowBase + wave * 32 + mi * 16 + quad * 4 + reg;
                if (grow < N) {
                    float v = acc[mi][ni][reg] + bv;
                    if (relu_out) v = fmaxf(v, 0.f);
                    s1[ni] += v;
                    s2[ni] += v * v;
                    if (out_bf16)
                        ((unsigned short*)Y)[(size_t)grow * HID + gcol] = f2bf(v);
                    else
                        ((float*)Y)[(size_t)grow * HID + gcol] = v;
                }
            }
        }
    }

    if (Sout) {
        // combine lanes sharing the same l16 (16 lanes apart) within the wave
#pragma unroll
        for (int ni = 0; ni < 8; ++ni) {
            s1[ni] += __shfl_xor(s1[ni], 16);
            s1[ni] += __shfl_xor(s1[ni], 32);
            s2[ni] += __shfl_xor(s2[ni], 16);
            s2[ni] += __shfl_xor(s2[ni], 32);
        }
        if (lane < 16) {
#pragma unroll
            for (int ni = 0; ni < 8; ++ni) {
                sred[wave][ni * 16 + l16] = s1[ni];
                sred[wave][128 + ni * 16 + l16] = s2[ni];
            }
        }
        __syncthreads();
        float v = sred[0][t & 255];
        if (t < 256) {
            v = sred[0][t] + sred[1][t] + sred[2][t] + sred[3][t];
            atomicAdd(&Sout[(blockIdx.x & 15) * 256 + t], v);
        }
    }
}

// ---------------- aggregation + fused GraphNorm stats ----------------
// Wave-per-row CSR gather (bf16 H), 4 rows per wave, 8-deep unroll.
#define AGG_R 4  // rows per wave -> 16 rows per block

__global__ __launch_bounds__(256) void k_agg(
    const unsigned short* __restrict__ H, const int2* __restrict__ es,
    const unsigned* __restrict__ endp, const unsigned* __restrict__ cnt,
    float* __restrict__ M, float* __restrict__ Spart, int N) {
    __shared__ float sb[4][256];
    int t = threadIdx.x;
    int wv = t >> 6, lane = t & 63;
    int fo = lane * 2;
    int rowBase = blockIdx.x * (4 * AGG_R) + wv * AGG_R;
    float s1a = 0.f, s1b = 0.f, s2a = 0.f, s2b = 0.f;

    for (int j = 0; j < AGG_R; ++j) {
        int rowi = rowBase + j;
        if (rowi >= N) break;
        unsigned e = endp[rowi];
        unsigned p = e - cnt[rowi];
        float a0 = 0.f, a1 = 0.f;
        for (; p + 7 < e; p += 8) {
            int2 ee[8];
            unsigned hh[8];
#pragma unroll
            for (int q = 0; q < 8; ++q) ee[q] = es[p + q];
#pragma unroll
            for (int q = 0; q < 8; ++q)
                hh[q] = *(const unsigned*)&H[(size_t)ee[q].x * HID + fo];
#pragma unroll
            for (int q = 0; q < 8; ++q) {
                float w = __int_as_float(ee[q].y);
                a0 = fmaf(w, bflo(hh[q]), a0);
                a1 = fmaf(w, bfhi(hh[q]), a1);
            }
        }
        for (; p < e; ++p) {
            int2 e0 = es[p];
            unsigned h0 = *(const unsigned*)&H[(size_t)e0.x * HID + fo];
            float w0 = __int_as_float(e0.y);
            a0 = fmaf(w0, bflo(h0), a0);
            a1 = fmaf(w0, bfhi(h0), a1);
        }
        s1a += a0; s1b += a1;
        s2a += a0 * a0; s2b += a1 * a1;
        *(float2*)&M[(size_t)rowi * HID + fo] = make_float2(a0, a1);
    }

    sb[wv][fo] = s1a;
    sb[wv][fo + 1] = s1b;
    sb[wv][128 + fo] = s2a;
    sb[wv][128 + fo + 1] = s2b;
    __syncthreads();
    {
        float v = sb[0][t] + sb[1][t] + sb[2][t] + sb[3][t];
        atomicAdd(&Spart[(blockIdx.x & 15) * 256 + t], v);
    }
}

// A = gamma*rsqrt(var+eps); B = beta - A*alpha*mu (sums 16 stripes)
__global__ void k_finalize(const float* __restrict__ S, const float* __restrict__ gamma,
                           const float* __restrict__ beta, const float* __restrict__ alpha,
                           float* __restrict__ AB, float invN) {
    int f = threadIdx.x;
    float sum = 0.f, sq = 0.f;
#pragma unroll
    for (int c = 0; c < 16; ++c) {
        sum += S[c * 256 + f];
        sq += S[c * 256 + 128 + f];
    }
    float mu = sum * invN;
    float ex2 = sq * invN;
    float a = alpha[f];
    float var = ex2 - 2.f * a * mu * mu + a * a * mu * mu;
    float rs = rsqrtf(var + 1e-5f);
    float A = gamma[f] * rs;
    float B = beta[f] - A * a * mu;
    AB[f] = A;
    AB[HID + f] = B;
}

// ---------------------------------------------------------------------------
extern "C" void kernel_launch(void* const* d_in, const int* in_sizes, int n_in,
                              void* d_out, int out_size, void* d_ws, size_t ws_size,
                              hipStream_t stream) {
    const int*   x_idx = (const int*)d_in[0];
    const int*   ei    = (const int*)d_in[1];
    const float* ew    = (const float*)d_in[2];
    const float* emb   = (const float*)d_in[3];
    const float* Wt    = (const float*)d_in[4];
    const float* bt    = (const float*)d_in[5];
    const float* Wc    = (const float*)d_in[6];
    const float* bc    = (const float*)d_in[7];
    const float* cg_g  = (const float*)d_in[8];
    const float* cg_b  = (const float*)d_in[9];
    const float* cg_a  = (const float*)d_in[10];
    const float* gn_g  = (const float*)d_in[11];
    const float* gn_b  = (const float*)d_in[12];
    const float* gn_a  = (const float*)d_in[13];
    const int N = in_sizes[0];
    const int E = in_sizes[2];
    const int* row = ei;
    const int* col = ei + E;

    char* ws = (char*)d_ws;
    size_t off = 0;
    auto alloc = [&](size_t bytes) -> void* {
        size_t o = (off + 511) & ~(size_t)511;
        off = o + bytes;
        return (void*)(ws + o);
    };
    const int SSTRIDE = 16 * 256;  // floats per stats stage
    unsigned* cursor = (unsigned*)alloc(NB * 4);             // zeroed
    float*    Spart  = (float*)alloc(5 * SSTRIDE * 4);       // zeroed
    size_t zero_end = off;
    unsigned* outbase = (unsigned*)alloc(NB * 4);
    unsigned* endp    = (unsigned*)alloc((size_t)N * 4);
    unsigned* cnt     = (unsigned*)alloc((size_t)N * 4);
    float*    AB      = (float*)alloc(5 * 256 * 4);
    unsigned short* WtT = (unsigned short*)alloc((size_t)3 * 128 * 128 * 2);
    unsigned short* WcT = (unsigned short*)alloc((size_t)3 * 128 * 256 * 2);
    int2*     binned  = (int2*)alloc((size_t)NB * CAPB * 8); // 33.6 MB
    int2*     edge_s  = (int2*)alloc((size_t)E * 8);         // 25.6 MB
    unsigned short* H = (unsigned short*)alloc((size_t)N * HID * 2);
    float*    X       = (float*)alloc((size_t)N * HID * 4);
    float*    M       = (float*)alloc((size_t)N * HID * 4);
    if (off > ws_size) {
        fprintf(stderr, "kernel_launch: ws too small (%zu > %zu)\n", off, ws_size);
        return;
    }

    hipMemsetAsync(d_ws, 0, zero_end, stream);

    k_prepw<<<(3 * 128 * 128 + 3 * 256 * 128 + 255) / 256, 256, 0, stream>>>(Wt, Wc, WtT, WcT);
    k_binA<<<(E + TILE_A - 1) / TILE_A, 256, 0, stream>>>(row, col, ew, binned, cursor, E);
    k_bscan<<<1, 256, 0, stream>>>(cursor, outbase);
    k_binB<<<NB, 256, 0, stream>>>(binned, cursor, outbase, edge_s, endp, cnt, N);

    int gemm_blocks = (N + GM_ROWS - 1) / GM_ROWS;
    auto gemm = [&](const float* X1, const int* G1, const float* AB1, int rl1,
                    const float* X2, const int* G2, const float* AB2, int rl2,
                    const unsigned short* Wn, int Kpitch, int nstage,
                    const float* bias, void* Y, int relu_out, int out_bf16,
                    float* Sout) {
        k_gemm<<<gemm_blocks, 256, 0, stream>>>(X1, G1, AB1, rl1, X2, G2, AB2, rl2,
                                                Wn, Kpitch, nstage, bias, Y,
                                                relu_out, out_bf16, Sout, N);
    };
    int aggB = (N + 4 * AGG_R - 1) / (4 * AGG_R);
    auto agg = [&](int stage) {
        k_agg<<<aggB, 256, 0, stream>>>(H, edge_s, endp, cnt, M,
                                        Spart + stage * SSTRIDE, N);
    };
    auto fin = [&](int stage, const float* g, const float* b, const float* a) {
        k_finalize<<<1, 128, 0, stream>>>(Spart + stage * SSTRIDE, g, b, a,
                                          AB + stage * 256, 1.0f / (float)N);
    };

    // ---- Layer 0 ----  (x0 = emb[x_idx], gathered in-staging)
    gemm(emb, x_idx, nullptr, 0, nullptr, nullptr, nullptr, 0, WtT, 128, 1, bt,
         H, 1, 1, nullptr);
    agg(0);
    fin(0, cg_g, cg_b, cg_a);
    gemm(M, nullptr, AB + 0 * 256, 0, emb, x_idx, nullptr, 0, WcT, 256, 2, bc,
         X, 0, 0, Spart + 1 * SSTRIDE);
    fin(1, gn_g, gn_b, gn_a);

    // ---- Layer 1 ----  (x1 = relu(gn0(y0)) applied on load via AB1)
    gemm(X, nullptr, AB + 1 * 256, 1, nullptr, nullptr, nullptr, 0,
         WtT + 16384, 128, 1, bt + 128, H, 1, 1, nullptr);
    agg(2);
    fin(2, cg_g + 128, cg_b + 128, cg_a + 128);
    gemm(M, nullptr, AB + 2 * 256, 0, X, nullptr, AB + 1 * 256, 1,
         WcT + 32768, 256, 2, bc + 128, X, 0, 0, Spart + 3 * SSTRIDE);
    fin(3, gn_g + 128, gn_b + 128, gn_a + 128);

    // ---- Layer 2 ----  (x2 = relu(gn1(y1)) applied on load via AB3)
    gemm(X, nullptr, AB + 3 * 256, 1, nullptr, nullptr, nullptr, 0,
         WtT + 2 * 16384, 128, 1, bt + 256, H, 1, 1, nullptr);
    agg(4);
    fin(4, cg_g + 256, cg_b + 256, cg_a + 256);
    gemm(M, nullptr, AB + 4 * 256, 0, X, nullptr, AB + 3 * 256, 1,
         WcT + 2 * 32768, 256, 2, bc + 256, d_out, 0, 0, nullptr);
}